// Round 1
// 114.272 us; speedup vs baseline: 1.0364x; 1.0364x over previous
//
#include <hip/hip_runtime.h>
#include <math.h>

#define NATOMS 512
#define TPB 256
#define WPB 4                 // waves per block; one wave = one batch element
#define FPE (3 * NATOMS)      // 1536 floats per element per array

// DPP-based 64-lane sum on the VALU pipe (no LDS-pipe traffic, no lgkmcnt).
// Sequence: row_shr 1/2/4/8 (row totals at lanes 15/31/47/63), row_bcast:15
// (lane31 += lane15; lane63 += lane47), row_bcast:31 (lane63 += lane31)
// -> full wave sum in lane 63. bound_ctrl=true: invalid source reads 0.
template <int CTRL>
__device__ __forceinline__ float dpp_add(float x) {
    const int yi = __builtin_amdgcn_update_dpp(
        0, __float_as_int(x), CTRL, 0xf, 0xf, true);
    return x + __int_as_float(yi);
}
__device__ __forceinline__ float wave_sum63(float x) {
    x = dpp_add<0x111>(x);  // row_shr:1
    x = dpp_add<0x112>(x);  // row_shr:2
    x = dpp_add<0x114>(x);  // row_shr:4
    x = dpp_add<0x118>(x);  // row_shr:8
    x = dpp_add<0x142>(x);  // row_bcast:15
    x = dpp_add<0x143>(x);  // row_bcast:31
    return x;               // lane 63 holds the wave total
}

// ---------------- Kernel 1: streaming reduction ----------------
// One wave per element, direct-to-VGPR loads (no LDS: data has zero reuse,
// staging was a wasted round-trip + a 48KB occupancy cap + a vmcnt(0) drain).
// Each lane owns atoms {lane, lane+64, ...}: a chunk load is dwordx3 at
// 12 B/lane stride = 768 B fully contiguous per wave per array.
// num_atoms is wave-uniform -> loop only over ceil(na/64) chunks, skipping
// the padding reads entirely (~44% of HBM traffic on average).
__global__ __launch_bounds__(TPB) void kabsch_reduce_kernel(
    const float* __restrict__ inp,
    const float* __restrict__ tgt,
    const int* __restrict__ num_atoms,
    float* __restrict__ partial,   // [B][16]
    int B)
{
    const int wave = threadIdx.x >> 6;
    const int lane = threadIdx.x & 63;
    const int b = blockIdx.x * WPB + wave;
    if (b >= B) return;

    const int na = num_atoms[b];        // wave-uniform -> scalar load
    int kmax = (na + 63) >> 6;          // chunks of 64 atoms, 1..8
    if (kmax < 1) kmax = 1;
    if (kmax > 8) kmax = 8;

    const float* gs = inp + (size_t)b * FPE + 3 * lane;
    const float* gd = tgt + (size_t)b * FPE + 3 * lane;

    float v[16];
    #pragma unroll
    for (int i = 0; i < 16; ++i) v[i] = 0.f;

    // 1-deep software pipeline: chunk k+1's loads are in flight while
    // chunk k is accumulated (compiler emits counted vmcnt, no full drain).
    float3 scur = *(const float3*)gs;
    float3 dcur = *(const float3*)gd;

    for (int k = 0; k < kmax; ++k) {
        float3 snxt = scur, dnxt = dcur;
        if (k + 1 < kmax) {             // wave-uniform branch
            snxt = *(const float3*)(gs + 192 * (k + 1));
            dnxt = *(const float3*)(gd + 192 * (k + 1));
        }
        const int atom = (k << 6) + lane;
        const float m = (atom < na) ? 1.f : 0.f;   // only last chunk masks
        const float sx = scur.x * m, sy = scur.y * m, sz = scur.z * m;
        const float dx = dcur.x * m, dy = dcur.y * m, dz = dcur.z * m;
        v[0]  += sx * dx;  v[1]  += sx * dy;  v[2]  += sx * dz;
        v[3]  += sy * dx;  v[4]  += sy * dy;  v[5]  += sy * dz;
        v[6]  += sz * dx;  v[7]  += sz * dy;  v[8]  += sz * dz;
        v[9]  += sx;  v[10] += sy;  v[11] += sz;
        v[12] += dx;  v[13] += dy;  v[14] += dz;
        v[15] += sx * sx + sy * sy + sz * sz + dx * dx + dy * dy + dz * dz;
        scur = snxt; dcur = dnxt;
    }

    // VALU-pipe wave reduction; totals valid in lane 63.
    #pragma unroll
    for (int i = 0; i < 16; ++i) v[i] = wave_sum63(v[i]);

    if (lane == 63) {
        float4* p = (float4*)(partial + (size_t)b * 16);
        p[0] = make_float4(v[0],  v[1],  v[2],  v[3]);
        p[1] = make_float4(v[4],  v[5],  v[6],  v[7]);
        p[2] = make_float4(v[8],  v[9],  v[10], v[11]);
        p[3] = make_float4(v[12], v[13], v[14], v[15]);
    }
}

// ---------------- Kernel 2: per-element epilogue ----------------
// One thread per batch element; fully parallel f64 Cardano eigen-solve.
// Kept separate: fusing it into kernel 1 would run ~500+ f64 ops (acos/cos
// libm expansions) with 1/64 lanes active per wave, adding ~10us/CU of
// wave-serial VALU against a ~9us memory envelope.
__global__ __launch_bounds__(TPB) void kabsch_epilogue_kernel(
    const float* __restrict__ partial,
    const int* __restrict__ num_atoms,
    float* __restrict__ out,
    int B)
{
    const int b = blockIdx.x * TPB + threadIdx.x;
    if (b >= B) return;

    const float4* p = (const float4*)(partial + (size_t)b * 16);
    const float4 r0 = p[0], r1 = p[1], r2 = p[2], r3 = p[3];
    float v[16] = { r0.x, r0.y, r0.z, r0.w,
                    r1.x, r1.y, r1.z, r1.w,
                    r2.x, r2.y, r2.z, r2.w,
                    r3.x, r3.y, r3.z, r3.w };

    const int na = num_atoms[b];
    const double n = (double)na;
    const double sx = (double)v[9],  sy = (double)v[10], sz = (double)v[11];
    const double tx = (double)v[12], ty = (double)v[13], tz = (double)v[14];

    double R[3][3];
    R[0][0] = (double)v[0] - sx * tx / n;
    R[0][1] = (double)v[1] - sx * ty / n;
    R[0][2] = (double)v[2] - sx * tz / n;
    R[1][0] = (double)v[3] - sy * tx / n;
    R[1][1] = (double)v[4] - sy * ty / n;
    R[1][2] = (double)v[5] - sy * tz / n;
    R[2][0] = (double)v[6] - sz * tx / n;
    R[2][1] = (double)v[7] - sz * ty / n;
    R[2][2] = (double)v[8] - sz * tz / n;

    const double sq = (double)v[15] - (sx * sx + sy * sy + sz * sz
                                     + tx * tx + ty * ty + tz * tz) / n;

    const double detR =
        R[0][0] * (R[1][1] * R[2][2] - R[1][2] * R[2][1])
      - R[0][1] * (R[1][0] * R[2][2] - R[1][2] * R[2][0])
      + R[0][2] * (R[1][0] * R[2][1] - R[1][1] * R[2][0]);

    double A00 = R[0][0]*R[0][0] + R[1][0]*R[1][0] + R[2][0]*R[2][0];
    double A11 = R[0][1]*R[0][1] + R[1][1]*R[1][1] + R[2][1]*R[2][1];
    double A22 = R[0][2]*R[0][2] + R[1][2]*R[1][2] + R[2][2]*R[2][2];
    double A01 = R[0][0]*R[0][1] + R[1][0]*R[1][1] + R[2][0]*R[2][1];
    double A02 = R[0][0]*R[0][2] + R[1][0]*R[1][2] + R[2][0]*R[2][2];
    double A12 = R[0][1]*R[0][2] + R[1][1]*R[1][2] + R[2][1]*R[2][2];

    double e0, e1, e2;  // descending
    const double p1 = A01*A01 + A02*A02 + A12*A12;
    if (p1 < 1e-30) {
        e0 = A00; e1 = A11; e2 = A22;
        double tmp;
        if (e0 < e1) { tmp = e0; e0 = e1; e1 = tmp; }
        if (e1 < e2) { tmp = e1; e1 = e2; e2 = tmp; }
        if (e0 < e1) { tmp = e0; e0 = e1; e1 = tmp; }
    } else {
        const double q  = (A00 + A11 + A22) / 3.0;
        const double b00 = A00 - q, b11 = A11 - q, b22 = A22 - q;
        const double p2 = b00*b00 + b11*b11 + b22*b22 + 2.0 * p1;
        const double pp = sqrt(p2 / 6.0);
        const double ip = 1.0 / pp;
        const double B00 = b00*ip, B11 = b11*ip, B22 = b22*ip;
        const double B01 = A01*ip, B02 = A02*ip, B12 = A12*ip;
        double r = 0.5 * (B00 * (B11 * B22 - B12 * B12)
                        - B01 * (B01 * B22 - B12 * B02)
                        + B02 * (B01 * B12 - B11 * B02));
        if (r < -1.0) r = -1.0;
        if (r >  1.0) r =  1.0;
        const double phi = acos(r) / 3.0;
        e0 = q + 2.0 * pp * cos(phi);
        e2 = q + 2.0 * pp * cos(phi + 2.0943951023931953);  // +2pi/3
        e1 = 3.0 * q - e0 - e2;
    }

    const double S0 = sqrt(e0 > 0.0 ? e0 : 0.0);
    const double S1 = sqrt(e1 > 0.0 ? e1 : 0.0);
    const double S2 = sqrt(e2 > 0.0 ? e2 : 0.0);
    const double dsgn = (detR > 0.0) ? 1.0 : ((detR < 0.0) ? -1.0 : 0.0);
    const double trace_opt = S0 + S1 + dsgn * S2;

    double msd = (sq - 2.0 * trace_opt) / n;
    if (msd < 0.0) msd = 0.0;
    out[b] = (float)sqrt(msd);
}

extern "C" void kernel_launch(void* const* d_in, const int* in_sizes, int n_in,
                              void* d_out, int out_size, void* d_ws, size_t ws_size,
                              hipStream_t stream) {
    const float* inp = (const float*)d_in[0];
    const float* tgt = (const float*)d_in[1];
    const int* num_atoms = (const int*)d_in[2];
    float* out = (float*)d_out;
    float* partial = (float*)d_ws;  // B*16 floats = 512 KB

    const int B = in_sizes[0] / FPE;
    const int blocks1 = (B + WPB - 1) / WPB;
    kabsch_reduce_kernel<<<blocks1, TPB, 0, stream>>>(inp, tgt, num_atoms, partial, B);
    const int blocks2 = (B + TPB - 1) / TPB;
    kabsch_epilogue_kernel<<<blocks2, TPB, 0, stream>>>(partial, num_atoms, out, B);
}